// Round 8
// baseline (134.270 us; speedup 1.0000x reference)
//
#include <hip/hip_runtime.h>

// ActionVectorQuantizer: z [8*32768, 256] f32, emb [8, 256] f32
// out0 = emb[argmin_c ||z-e_c||^2] (f32), out1 = idx stored as f32.
//
// Layout: lane = (c2=bit0, g=bits1..5). Lane owns dims 8g..8g+7 (chunks
// lane, lane^1) and codes {4*c2+m}. Per token: in-lane f64 dots, fold
// masks {2,4}. Every 8 tokens: transpose-fold masks {8,16,32} (token
// tau = bits3..5), packed-key argmin masks {1,2,4}. All f64 (exact f32
// products) -> argmin identical to the verified round-3/7 kernels.
//
// Round-8 delta vs the verified 112.8us kernel: depth-4 z prefetch
// (was depth-2). Diagnosis: VALUBusy ~20% AND hbm ~35% -> latency-bound;
// 900-cyc HBM latency vs ~250 cyc/iter own work and ~3 waves/SIMD.
// Depth 4 -> latency/4 = 225 < 250 -> hidden. +16 VGPR, stays < 128 cap.

#define NC   8
#define DIM  256
#define TPW  32            // tokens per wave
#define WPB  4             // waves per block
#define THREADS (WPB * 64)

typedef float f32x4 __attribute__((ext_vector_type(4)));

__global__ __launch_bounds__(THREADS, 4)
void vq_kernel(const float* __restrict__ z, const float* __restrict__ emb,
               float* __restrict__ zq, float* __restrict__ fidx)
{
    const int lane = threadIdx.x & 63;
    const int wid  = blockIdx.x * WPB + (threadIdx.x >> 6);

    const int c2 = lane & 1;
    const int b1 = (lane >> 1) & 1, b2 = (lane >> 2) & 1;
    const int b3 = (lane >> 3) & 1, b4 = (lane >> 4) & 1, b5 = (lane >> 5) & 1;
    const int kappa = 4 * c2 + 2 * b1 + b2;     // code this lane owns post-fold
    const int gidx  = lane & 7;                 // lane within 8-lane group
    const int tau   = 4 * b3 + 2 * b4 + b5;     // batch-local token post-transpose

    // emb fragments in f32 (rematerializable cvt at use keeps VGPR low)
    float e32[4][8];
#pragma unroll
    for (int m = 0; m < 4; ++m) {
        const int row = 4 * c2 + m;
        const float4 ea = *reinterpret_cast<const float4*>(emb + row * DIM + 4 * lane);
        const float4 eb = *reinterpret_cast<const float4*>(emb + row * DIM + 4 * (lane ^ 1));
        e32[m][0] = ea.x; e32[m][1] = ea.y; e32[m][2] = ea.z; e32[m][3] = ea.w;
        e32[m][4] = eb.x; e32[m][5] = eb.y; e32[m][6] = eb.z; e32[m][7] = eb.w;
    }

    // ||e_kappa||^2 via the same fold pipeline (one-time, f64-exact)
    double es[4];
#pragma unroll
    for (int m = 0; m < 4; ++m) {
        double s = 0.0;
#pragma unroll
        for (int j = 0; j < 8; ++j) {
            const double e = (double)e32[m][j];
            s += e * e;
        }
        es[m] = s;
    }
    double est[2];
#pragma unroll
    for (int i = 0; i < 2; ++i) {
        double keep = b1 ? es[i + 2] : es[i];
        double send = b1 ? es[i]     : es[i + 2];
        est[i] = keep + __shfl_xor(send, 2, 64);
    }
    double esv = (b2 ? est[1] : est[0]) + __shfl_xor(b2 ? est[0] : est[1], 4, 64);
    esv += __shfl_xor(esv, 8, 64);
    esv += __shfl_xor(esv, 16, 64);
    esv += __shfl_xor(esv, 32, 64);
    const double esq_my = esv;   // ||e_kappa||^2, exact f64

    const long long tok0 = (long long)wid * TPW;
    const float4* zf4 = reinterpret_cast<const float4*>(z + tok0 * DIM);

    // depth-4 prefetch pipeline (static names; rotation is free inside the
    // fully-unrolled inner loop -> no runtime-indexed arrays, no scratch)
    float4 cA  = zf4[lane],           cB  = zf4[lane ^ 1];           // token 0
    float4 p1A = zf4[64 + lane],      p1B = zf4[64 + (lane ^ 1)];    // token 1
    float4 p2A = zf4[128 + lane],     p2B = zf4[128 + (lane ^ 1)];   // token 2
    float4 p3A = zf4[192 + lane],     p3B = zf4[192 + (lane ^ 1)];   // token 3

    double val[8];

#pragma unroll 1
    for (int b = 0; b < 4; ++b) {
#pragma unroll
        for (int t = 0; t < 8; ++t) {
            const int bt  = b * 8 + t;
            const int nxt = (bt + 4 <= TPW - 1) ? (bt + 4) : (TPW - 1);
            float4 p4A = zf4[nxt * 64 + lane];
            float4 p4B = zf4[nxt * 64 + (lane ^ 1)];

            // chunk A then chunk B: short f64 temp lifetimes.
            // (double)e32[..] is exact -> products identical to all-f64.
            double acc[4];
            {
                const double z0 = cA.x, z1 = cA.y, z2 = cA.z, z3 = cA.w;
#pragma unroll
                for (int m = 0; m < 4; ++m)
                    acc[m] = (z0 * (double)e32[m][0] + z1 * (double)e32[m][1])
                           + (z2 * (double)e32[m][2] + z3 * (double)e32[m][3]);
            }
            {
                const double z4 = cB.x, z5 = cB.y, z6 = cB.z, z7 = cB.w;
#pragma unroll
                for (int m = 0; m < 4; ++m)
                    acc[m] += (z4 * (double)e32[m][4] + z5 * (double)e32[m][5])
                            + (z6 * (double)e32[m][6] + z7 * (double)e32[m][7]);
            }

            // per-token fold: masks {2,4} -> 1 partial/lane (code kappa, 32 dims)
            double ft[2];
#pragma unroll
            for (int i = 0; i < 2; ++i) {
                double keep = b1 ? acc[i + 2] : acc[i];
                double send = b1 ? acc[i]     : acc[i + 2];
                ft[i] = keep + __shfl_xor(send, 2, 64);
            }
            val[t] = (b2 ? ft[1] : ft[0]) + __shfl_xor(b2 ? ft[0] : ft[1], 4, 64);

            // rotate the 4-deep pipeline (static names, unrolled -> free)
            cA = p1A;  cB = p1B;
            p1A = p2A; p1B = p2B;
            p2A = p3A; p2B = p3B;
            p3A = p4A; p3B = p4B;
        }

        // ===== batched tail for tokens b*8 .. b*8+7 =====
        // transpose-fold masks {8,16,32}: lane ends with full dot for
        // (token tau, code kappa)
        double tt[4];
#pragma unroll
        for (int i = 0; i < 4; ++i) {
            double keep = b3 ? val[i + 4] : val[i];
            double send = b3 ? val[i]     : val[i + 4];
            tt[i] = keep + __shfl_xor(send, 8, 64);
        }
        double uu[2];
#pragma unroll
        for (int i = 0; i < 2; ++i) {
            double keep = b4 ? tt[i + 2] : tt[i];
            double send = b4 ? tt[i]     : tt[i + 2];
            uu[i] = keep + __shfl_xor(send, 16, 64);
        }
        const double dot = (b5 ? uu[1] : uu[0]) + __shfl_xor(b5 ? uu[0] : uu[1], 32, 64);

        // argmin of ||z||^2 + ||e||^2 - 2 z.e == argmin of ||e||^2 - 2 z.e
        const double dist = esq_my - 2.0 * dot;

        // order-preserving f64 -> u64 key, code idx in low 3 bits
        // (equal dists -> lower code wins == numpy first-occurrence argmin)
        unsigned long long u = (unsigned long long)__double_as_longlong(dist);
        u = (u >> 63) ? ~u : (u | 0x8000000000000000ULL);
        unsigned long long key = (u & ~7ULL) | (unsigned long long)kappa;
#pragma unroll
        for (int m = 1; m <= 4; m <<= 1) {
            unsigned long long ok = __shfl_xor(key, m, 64);
            key = (ok < key) ? ok : key;
        }
        const int widx = (int)(key & 7ULL);   // winner for token tau (group-wide)

        // cooperative z_q write: group owns token tau; round j writes the
        // contiguous 128B span chunks {8j..8j+7} (lane -> chunk gidx+8j).
        // Nontemporal: full-line streaming writes, never re-read (and they
        // don't evict the L3-resident z stream).
        const long long row = tok0 + b * 8 + tau;
        float* qrow = zq + row * DIM;
        const float* erow = emb + widx * DIM;
#pragma unroll
        for (int j = 0; j < 8; ++j) {
            const int ch = gidx + 8 * j;
            const f32x4 q = *reinterpret_cast<const f32x4*>(erow + 4 * ch);
            __builtin_nontemporal_store(q, reinterpret_cast<f32x4*>(qrow + 4 * ch));
        }
        if (gidx == 0) fidx[row] = (float)widx;
    }
}

extern "C" void kernel_launch(void* const* d_in, const int* in_sizes, int n_in,
                              void* d_out, int out_size, void* d_ws, size_t ws_size,
                              hipStream_t stream)
{
    const float* z   = (const float*)d_in[0];
    const float* emb = (const float*)d_in[1];
    float* out = (float*)d_out;

    const long long ntok = (long long)in_sizes[0] / DIM;   // 262144
    float* zq   = out;
    float* fidx = out + (size_t)ntok * DIM;

    const int blocks = (int)(ntok / (TPW * WPB));          // 2048

    vq_kernel<<<blocks, THREADS, 0, stream>>>(z, emb, zq, fidx);
}

// Round 9
// 102.187 us; speedup vs baseline: 1.3140x; 1.3140x over previous
//
#include <hip/hip_runtime.h>

// ActionVectorQuantizer: z [8*32768, 256] f32, emb [8, 256] f32
// out0 = emb[argmin_c ||z-e_c||^2] (f32), out1 = idx stored as f32.
//
// Layout: lane = (c2=bit0, g=bits1..5). Lane owns dims 8g..8g+7 (chunks
// lane, lane^1) and codes {4*c2+m}. Per token: in-lane f64 dots, fold
// masks {2,4}. Every 8 tokens: transpose-fold masks {8,16,32} (token
// tau = bits3..5), packed-key argmin masks {1,2,4}. All f64 (exact f32
// products) -> argmin identical to the verified round-3/7 kernels.
//
// Round-9: best-of-both. e64 kept in f64 (no 32 remat-cvts/token; round 3
// proved spill-free under launch_bounds(256,3)), depth-3 prefetch
// (round 8's depth-4 under the (256,4)=64-reg trap spilled: WRITE +16MB),
// NT full-line z_q stores (protect L3-resident z: FETCH 136MB).

#define NC   8
#define DIM  256
#define TPW  32            // tokens per wave
#define WPB  4             // waves per block
#define THREADS (WPB * 64)

typedef float f32x4 __attribute__((ext_vector_type(4)));

__global__ __launch_bounds__(THREADS, 3)
void vq_kernel(const float* __restrict__ z, const float* __restrict__ emb,
               float* __restrict__ zq, float* __restrict__ fidx)
{
    const int lane = threadIdx.x & 63;
    const int wid  = blockIdx.x * WPB + (threadIdx.x >> 6);

    const int c2 = lane & 1;
    const int b1 = (lane >> 1) & 1, b2 = (lane >> 2) & 1;
    const int b3 = (lane >> 3) & 1, b4 = (lane >> 4) & 1, b5 = (lane >> 5) & 1;
    const int kappa = 4 * c2 + 2 * b1 + b2;     // code this lane owns post-fold
    const int gidx  = lane & 7;                 // lane within 8-lane group
    const int tau   = 4 * b3 + 2 * b4 + b5;     // batch-local token post-transpose

    // emb fragments in f64: e64[m][0..3] <-> chunk `lane`, [4..7] <-> chunk `lane^1`
    double e64[4][8];
#pragma unroll
    for (int m = 0; m < 4; ++m) {
        const int row = 4 * c2 + m;
        const float4 ea = *reinterpret_cast<const float4*>(emb + row * DIM + 4 * lane);
        const float4 eb = *reinterpret_cast<const float4*>(emb + row * DIM + 4 * (lane ^ 1));
        e64[m][0] = ea.x; e64[m][1] = ea.y; e64[m][2] = ea.z; e64[m][3] = ea.w;
        e64[m][4] = eb.x; e64[m][5] = eb.y; e64[m][6] = eb.z; e64[m][7] = eb.w;
    }

    // ||e_kappa||^2 via the same fold pipeline (one-time, f64-exact)
    double es[4];
#pragma unroll
    for (int m = 0; m < 4; ++m) {
        double s = 0.0;
#pragma unroll
        for (int j = 0; j < 8; ++j) s += e64[m][j] * e64[m][j];
        es[m] = s;
    }
    double est[2];
#pragma unroll
    for (int i = 0; i < 2; ++i) {
        double keep = b1 ? es[i + 2] : es[i];
        double send = b1 ? es[i]     : es[i + 2];
        est[i] = keep + __shfl_xor(send, 2, 64);
    }
    double esv = (b2 ? est[1] : est[0]) + __shfl_xor(b2 ? est[0] : est[1], 4, 64);
    esv += __shfl_xor(esv, 8, 64);
    esv += __shfl_xor(esv, 16, 64);
    esv += __shfl_xor(esv, 32, 64);
    const double esq_my = esv;   // ||e_kappa||^2, exact f64

    const long long tok0 = (long long)wid * TPW;
    const float4* zf4 = reinterpret_cast<const float4*>(z + tok0 * DIM);

    // depth-3 prefetch pipeline (static names; rotation free when unrolled)
    float4 cA  = zf4[lane],       cB  = zf4[lane ^ 1];            // token 0
    float4 p1A = zf4[64 + lane],  p1B = zf4[64 + (lane ^ 1)];     // token 1
    float4 p2A = zf4[128 + lane], p2B = zf4[128 + (lane ^ 1)];    // token 2

    double val[8];

#pragma unroll 1
    for (int b = 0; b < 4; ++b) {
#pragma unroll
        for (int t = 0; t < 8; ++t) {
            const int bt  = b * 8 + t;
            const int nxt = (bt + 3 <= TPW - 1) ? (bt + 3) : (TPW - 1);
            float4 p3A = zf4[nxt * 64 + lane];
            float4 p3B = zf4[nxt * 64 + (lane ^ 1)];

            // chunk A then chunk B: short f64 temp lifetimes
            double acc[4];
            {
                const double z0 = cA.x, z1 = cA.y, z2 = cA.z, z3 = cA.w;
#pragma unroll
                for (int m = 0; m < 4; ++m)
                    acc[m] = (z0 * e64[m][0] + z1 * e64[m][1])
                           + (z2 * e64[m][2] + z3 * e64[m][3]);
            }
            {
                const double z4 = cB.x, z5 = cB.y, z6 = cB.z, z7 = cB.w;
#pragma unroll
                for (int m = 0; m < 4; ++m)
                    acc[m] += (z4 * e64[m][4] + z5 * e64[m][5])
                            + (z6 * e64[m][6] + z7 * e64[m][7]);
            }

            // per-token fold: masks {2,4} -> 1 partial/lane (code kappa, 32 dims)
            double ft[2];
#pragma unroll
            for (int i = 0; i < 2; ++i) {
                double keep = b1 ? acc[i + 2] : acc[i];
                double send = b1 ? acc[i]     : acc[i + 2];
                ft[i] = keep + __shfl_xor(send, 2, 64);
            }
            val[t] = (b2 ? ft[1] : ft[0]) + __shfl_xor(b2 ? ft[0] : ft[1], 4, 64);

            // rotate the 3-deep pipeline (static names)
            cA = p1A;  cB = p1B;
            p1A = p2A; p1B = p2B;
            p2A = p3A; p2B = p3B;
        }

        // ===== batched tail for tokens b*8 .. b*8+7 =====
        // transpose-fold masks {8,16,32}: lane ends with full dot for
        // (token tau, code kappa)
        double tt[4];
#pragma unroll
        for (int i = 0; i < 4; ++i) {
            double keep = b3 ? val[i + 4] : val[i];
            double send = b3 ? val[i]     : val[i + 4];
            tt[i] = keep + __shfl_xor(send, 8, 64);
        }
        double uu[2];
#pragma unroll
        for (int i = 0; i < 2; ++i) {
            double keep = b4 ? tt[i + 2] : tt[i];
            double send = b4 ? tt[i]     : tt[i + 2];
            uu[i] = keep + __shfl_xor(send, 16, 64);
        }
        const double dot = (b5 ? uu[1] : uu[0]) + __shfl_xor(b5 ? uu[0] : uu[1], 32, 64);

        // argmin of ||z||^2 + ||e||^2 - 2 z.e == argmin of ||e||^2 - 2 z.e
        const double dist = esq_my - 2.0 * dot;

        // order-preserving f64 -> u64 key, code idx in low 3 bits
        // (equal dists -> lower code wins == numpy first-occurrence argmin)
        unsigned long long u = (unsigned long long)__double_as_longlong(dist);
        u = (u >> 63) ? ~u : (u | 0x8000000000000000ULL);
        unsigned long long key = (u & ~7ULL) | (unsigned long long)kappa;
#pragma unroll
        for (int m = 1; m <= 4; m <<= 1) {
            unsigned long long ok = __shfl_xor(key, m, 64);
            key = (ok < key) ? ok : key;
        }
        const int widx = (int)(key & 7ULL);   // winner for token tau (group-wide)

        // cooperative z_q write: group owns token tau; round j writes the
        // contiguous 128B span chunks {8j..8j+7} (lane -> chunk gidx+8j).
        // Nontemporal: full-line streaming writes, never re-read (and they
        // don't evict the L3-resident z stream).
        const long long row = tok0 + b * 8 + tau;
        float* qrow = zq + row * DIM;
        const float* erow = emb + widx * DIM;
#pragma unroll
        for (int j = 0; j < 8; ++j) {
            const int ch = gidx + 8 * j;
            const f32x4 q = *reinterpret_cast<const f32x4*>(erow + 4 * ch);
            __builtin_nontemporal_store(q, reinterpret_cast<f32x4*>(qrow + 4 * ch));
        }
        if (gidx == 0) fidx[row] = (float)widx;
    }
}

extern "C" void kernel_launch(void* const* d_in, const int* in_sizes, int n_in,
                              void* d_out, int out_size, void* d_ws, size_t ws_size,
                              hipStream_t stream)
{
    const float* z   = (const float*)d_in[0];
    const float* emb = (const float*)d_in[1];
    float* out = (float*)d_out;

    const long long ntok = (long long)in_sizes[0] / DIM;   // 262144
    float* zq   = out;
    float* fidx = out + (size_t)ntok * DIM;

    const int blocks = (int)(ntok / (TPW * WPB));          // 2048

    vq_kernel<<<blocks, THREADS, 0, stream>>>(z, emb, zq, fidx);
}

// Round 10
// 95.081 us; speedup vs baseline: 1.4122x; 1.0747x over previous
//
#include <hip/hip_runtime.h>

// ActionVectorQuantizer: z [8*32768, 256] f32, emb [8, 256] f32
// out0 = emb[argmin_c ||z-e_c||^2] (f32), out1 = idx stored as f32.
//
// Math (unchanged, 4x-verified): lane = (c2=bit0, g=bits1..5); lane owns
// dims 8g..8g+7 (chunks lane, lane^1) and codes {4*c2+m}. Per token:
// in-lane f64 dots, fold masks {2,4}. Per 8-token batch: transpose-fold
// masks {8,16,32} (token tau = bits3..5), packed-key argmin masks {1,2,4}.
// All f64 (exact f32 products); first-occurrence tie-break.
//
// Round-10: per-wave LDS-staged deep pipeline (T3/T4, barrier-free).
// Diagnosis: depth-3 reg pipeline leaves ~2200 cyc/token/wave (latency-
// bound, VALUBusy 21%, hbm 2.5-4 TB/s vs 6.9 fill-rate); deeper reg
// pipelines spill (rounds 6/8). Fix: double-buffered 8-token (8 KB)
// per-wave LDS buffers staged via global_load_lds width-16 (1 instr/row,
// linear dst), counted inline-asm vmcnt per the op ledger:
//   S(b0) S(b1) | w8 C0 T0 S(b2) | w17 C1 T1 S(b3) | w17 C2 T2 | w9 C3 T3
// (younger-than-batch-b loads = next batch's 8 loads + prev tail's 9
// stores). 8 loads in flight/wave, zero VGPR cost for depth.

#define NC    8
#define DIM   256
#define TPW   32           // tokens per wave
#define WPB   2            // waves per block
#define THREADS (WPB * 64)
#define BATCH 8

typedef float f32x4 __attribute__((ext_vector_type(4)));

__global__ __launch_bounds__(THREADS, 2)
void vq_kernel(const float* __restrict__ z, const float* __restrict__ emb,
               float* __restrict__ zq, float* __restrict__ fidx)
{
    // 2 waves x 2 buffers x 8 tokens x 1KB = 32 KB/block -> 5 blocks/CU
    __shared__ float lds[WPB][2][BATCH * DIM];

    const int lane = threadIdx.x & 63;
    const int w    = threadIdx.x >> 6;
    const int wid  = blockIdx.x * WPB + w;

    const int c2 = lane & 1;
    const int b1 = (lane >> 1) & 1, b2 = (lane >> 2) & 1;
    const int b3 = (lane >> 3) & 1, b4 = (lane >> 4) & 1, b5 = (lane >> 5) & 1;
    const int kappa = 4 * c2 + 2 * b1 + b2;   // code this lane owns post-fold
    const int gidx  = lane & 7;               // lane within 8-lane group
    const int tau   = 4 * b3 + 2 * b4 + b5;   // batch-local token post-transpose

    // emb fragments in f64: [m][0..3] <-> chunk `lane`, [4..7] <-> chunk `lane^1`
    double e64[4][8];
#pragma unroll
    for (int m = 0; m < 4; ++m) {
        const int row = 4 * c2 + m;
        const float4 ea = *reinterpret_cast<const float4*>(emb + row * DIM + 4 * lane);
        const float4 eb = *reinterpret_cast<const float4*>(emb + row * DIM + 4 * (lane ^ 1));
        e64[m][0] = ea.x; e64[m][1] = ea.y; e64[m][2] = ea.z; e64[m][3] = ea.w;
        e64[m][4] = eb.x; e64[m][5] = eb.y; e64[m][6] = eb.z; e64[m][7] = eb.w;
    }

    // ||e_kappa||^2 via the same fold pipeline (one-time, f64-exact)
    double es[4];
#pragma unroll
    for (int m = 0; m < 4; ++m) {
        double s = 0.0;
#pragma unroll
        for (int j = 0; j < 8; ++j) s += e64[m][j] * e64[m][j];
        es[m] = s;
    }
    double est[2];
#pragma unroll
    for (int i = 0; i < 2; ++i) {
        double keep = b1 ? es[i + 2] : es[i];
        double send = b1 ? es[i]     : es[i + 2];
        est[i] = keep + __shfl_xor(send, 2, 64);
    }
    double esv = (b2 ? est[1] : est[0]) + __shfl_xor(b2 ? est[0] : est[1], 4, 64);
    esv += __shfl_xor(esv, 8, 64);
    esv += __shfl_xor(esv, 16, 64);
    esv += __shfl_xor(esv, 32, 64);
    const double esq_my = esv;   // ||e_kappa||^2, exact f64

    const long long tok0 = (long long)wid * TPW;

    double val[8];

    // ---- stage one 8-token batch into a per-wave LDS buffer ----
    // global_load_lds width=16: dst is wave-uniform base + lane*16 ->
    // linear row layout (exactly how we read it back).
    auto STAGE = [&](int bufi, int bidx) {
        const float* s = z + (tok0 + (long long)bidx * BATCH) * DIM + 4 * lane;
        float* d = &lds[w][bufi][0];
#pragma unroll
        for (int t = 0; t < BATCH; ++t)
            __builtin_amdgcn_global_load_lds(
                (const unsigned int*)(s + (size_t)t * DIM),
                (unsigned int*)(d + t * DIM), 16, 0, 0);
    };

    // ---- compute 8 tokens from an LDS buffer -> val[0..7] ----
    auto COMPUTE = [&](int bufi) {
        const float* bb = &lds[w][bufi][0];
#pragma unroll
        for (int t = 0; t < BATCH; ++t) {
            const float4 cA = *reinterpret_cast<const float4*>(bb + t * DIM + 4 * lane);
            const float4 cB = *reinterpret_cast<const float4*>(bb + t * DIM + 4 * (lane ^ 1));
            double acc[4];
            {
                const double z0 = cA.x, z1 = cA.y, z2 = cA.z, z3 = cA.w;
#pragma unroll
                for (int m = 0; m < 4; ++m)
                    acc[m] = (z0 * e64[m][0] + z1 * e64[m][1])
                           + (z2 * e64[m][2] + z3 * e64[m][3]);
            }
            {
                const double z4 = cB.x, z5 = cB.y, z6 = cB.z, z7 = cB.w;
#pragma unroll
                for (int m = 0; m < 4; ++m)
                    acc[m] += (z4 * e64[m][4] + z5 * e64[m][5])
                            + (z6 * e64[m][6] + z7 * e64[m][7]);
            }
            double ft[2];
#pragma unroll
            for (int i = 0; i < 2; ++i) {
                double keep = b1 ? acc[i + 2] : acc[i];
                double send = b1 ? acc[i]     : acc[i + 2];
                ft[i] = keep + __shfl_xor(send, 2, 64);
            }
            val[t] = (b2 ? ft[1] : ft[0]) + __shfl_xor(b2 ? ft[0] : ft[1], 4, 64);
        }
    };

    // ---- batched tail: transpose-fold, argmin, z_q + idx stores ----
    auto TAIL = [&](int bidx) {
        double tt[4];
#pragma unroll
        for (int i = 0; i < 4; ++i) {
            double keep = b3 ? val[i + 4] : val[i];
            double send = b3 ? val[i]     : val[i + 4];
            tt[i] = keep + __shfl_xor(send, 8, 64);
        }
        double uu[2];
#pragma unroll
        for (int i = 0; i < 2; ++i) {
            double keep = b4 ? tt[i + 2] : tt[i];
            double send = b4 ? tt[i]     : tt[i + 2];
            uu[i] = keep + __shfl_xor(send, 16, 64);
        }
        const double dot = (b5 ? uu[1] : uu[0]) + __shfl_xor(b5 ? uu[0] : uu[1], 32, 64);

        // argmin of ||z||^2 + ||e||^2 - 2 z.e == argmin of ||e||^2 - 2 z.e
        const double dist = esq_my - 2.0 * dot;

        // order-preserving f64 -> u64 key, code idx in low 3 bits
        unsigned long long u = (unsigned long long)__double_as_longlong(dist);
        u = (u >> 63) ? ~u : (u | 0x8000000000000000ULL);
        unsigned long long key = (u & ~7ULL) | (unsigned long long)kappa;
#pragma unroll
        for (int m = 1; m <= 4; m <<= 1) {
            unsigned long long ok = __shfl_xor(key, m, 64);
            key = (ok < key) ? ok : key;
        }
        const int widx = (int)(key & 7ULL);   // winner for token tau (group-wide)

        // cooperative z_q write (8 NT full-line stores + 1 idx store = 9 vmem)
        const long long row = tok0 + (long long)bidx * BATCH + tau;
        float* qrow = zq + row * DIM;
        const float* erow = emb + widx * DIM;
#pragma unroll
        for (int j = 0; j < 8; ++j) {
            const int ch = gidx + 8 * j;
            const f32x4 q = *reinterpret_cast<const f32x4*>(erow + 4 * ch);
            __builtin_nontemporal_store(q, reinterpret_cast<f32x4*>(qrow + 4 * ch));
        }
        if (gidx == 0) fidx[row] = (float)widx;
    };

    // ---- pipelined schedule (counted vmcnt; never 0 mid-loop) ----
    STAGE(0, 0);                 // 8 loads
    STAGE(1, 1);                 // 8 loads

    // batch 0: younger than batch-0 loads = batch-1's 8
    asm volatile("s_waitcnt vmcnt(8)" ::: "memory");
    __builtin_amdgcn_sched_barrier(0);
    COMPUTE(0); TAIL(0);         // 9 stores
    STAGE(0, 2);                 // 8 loads

    // batch 1: younger = tail0 stores (9) + batch-2 loads (8) = 17
    asm volatile("s_waitcnt vmcnt(17)" ::: "memory");
    __builtin_amdgcn_sched_barrier(0);
    COMPUTE(1); TAIL(1);
    STAGE(1, 3);

    // batch 2: younger = tail1 stores (9) + batch-3 loads (8) = 17
    asm volatile("s_waitcnt vmcnt(17)" ::: "memory");
    __builtin_amdgcn_sched_barrier(0);
    COMPUTE(0); TAIL(2);

    // batch 3: younger = tail2 stores (9)
    asm volatile("s_waitcnt vmcnt(9)" ::: "memory");
    __builtin_amdgcn_sched_barrier(0);
    COMPUTE(1); TAIL(3);
}

extern "C" void kernel_launch(void* const* d_in, const int* in_sizes, int n_in,
                              void* d_out, int out_size, void* d_ws, size_t ws_size,
                              hipStream_t stream)
{
    const float* z   = (const float*)d_in[0];
    const float* emb = (const float*)d_in[1];
    float* out = (float*)d_out;

    const long long ntok = (long long)in_sizes[0] / DIM;   // 262144
    float* zq   = out;
    float* fidx = out + (size_t)ntok * DIM;

    const int blocks = (int)(ntok / (TPW * WPB));          // 4096

    vq_kernel<<<blocks, THREADS, 0, stream>>>(z, emb, zq, fidx);
}